// Round 10
// baseline (226.790 us; speedup 1.0000x reference)
//
#include <hip/hip_runtime.h>
#include <hip/hip_bf16.h>

typedef unsigned short u16;
typedef unsigned int u32;
typedef short bf16x8 __attribute__((ext_vector_type(8)));
typedef float f32x4 __attribute__((ext_vector_type(4)));
typedef float f32x16 __attribute__((ext_vector_type(16)));

#define EPSV 1e-5f
// ws byte layout
#define WS_A3L   0                       // 128*32 bf16 [A3 | c3 | 0...] = 8 KB
#define WS_WB    8192                    // 128*128 bf16 = 32 KB
#define WS_WCAT  40960                   // 128*160 bf16 [wf2 | A1 | bias | 0] = 40 KB
#define WS_XH    81920                   // 2*65536*8 f32 x-transpose = 4 MB

union U4 { uint4 q; bf16x8 v; };

__device__ __forceinline__ u16 f2bf(float f) {
    union { __hip_bfloat16 h; u16 u; } cv;
    cv.h = __float2bfloat16(f);
    return cv.u;
}
// RNE pack of two f32 into packed bf16 pair (lo = a, hi = b) — pure integer ops
__device__ __forceinline__ u32 pack_rne(float a, float b) {
    u32 ua = __float_as_uint(a), ub = __float_as_uint(b);
    ua = ua + 0x7FFFu + ((ua >> 16) & 1u);
    ub = ub + 0x7FFFu + ((ub >> 16) & 1u);
    return (ua >> 16) | (ub & 0xFFFF0000u);
}
// 3-input max (clang fuses nested fmaxf to v_max3_f32)
__device__ __forceinline__ float max3f(float a, float b, float c) {
    return fmaxf(fmaxf(a, b), c);
}

// ---------------- setup: xhat (blocks 0..511) + prep (blocks 512..543) ----------
__global__ __launch_bounds__(256) void setup_kernel(
    const float* __restrict__ x,
    const float* g1, const float* b1, const float* m1, const float* v1,
    const float* w1, const float* c1b,
    const float* g2, const float* b2, const float* m2, const float* v2,
    const float* wA,
    const float* g3, const float* b3, const float* m3, const float* v3,
    const float* wB, const float* wf, const float* bfv,
    float* __restrict__ xh, u16* A3L, u16* wBh, u16* Wc)
{
    __shared__ float w1s[1024];
    __shared__ float c1s[128];
    __shared__ float s1[8], be1[8], s2[8], be2[8];
    __shared__ float w1fS[128][8];
    __shared__ float cbS[128];
    int bid = blockIdx.x, t = threadIdx.x;

    if (bid < 512) {
        // xhat: x transpose to [b][n][8ch] f32 rows (32B)
        int tg = (bid << 8) + t;
        int b = tg >> 16, n = tg & 65535;
        float4 a, c;
        a.x = x[(((b << 3) + 0) << 16) | n];
        a.y = x[(((b << 3) + 1) << 16) | n];
        a.z = x[(((b << 3) + 2) << 16) | n];
        a.w = x[(((b << 3) + 3) << 16) | n];
        c.x = x[(((b << 3) + 4) << 16) | n];
        c.y = x[(((b << 3) + 5) << 16) | n];
        c.z = x[(((b << 3) + 6) << 16) | n];
        c.w = x[(((b << 3) + 7) << 16) | n];
        float4* o = (float4*)xh + ((size_t)tg << 1);
        o[0] = a; o[1] = c;
        return;
    }
    int rb = bid - 512;                 // 0..31
    // distributed big copies (32 blocks)
    for (int j = (rb << 8) + t; j < 16384; j += 8192) {
        int o = j >> 7, c = j & 127;
        Wc[o * 160 + c] = f2bf(wf[o * 256 + 128 + c]);
    }
    {
        int j = (rb << 8) + t;          // 8192 packed u32 over 8192 threads
        ((u32*)wBh)[j] = pack_rne(wB[2 * j], wB[2 * j + 1]);
    }
    if (rb) return;

    // ---- fold (single block) ----
    for (int i = t; i < 1024; i += 256) w1s[i] = w1[i];
    if (t < 128) c1s[t] = c1b[t];
    if (t < 8) {
        float s = g1[t] * rsqrtf(v1[t] + EPSV); s1[t] = s; be1[t] = b1[t] - m1[t] * s;
        float u = g2[t] * rsqrtf(v2[t] + EPSV); s2[t] = u; be2[t] = b2[t] - m2[t] * u;
    }
    __syncthreads();

    // fold wf_left @ [w1 | c1b]: thread (o, half) does 4 i's (+ cb on half 1)
    {
        int o = t >> 1, half = t & 1;
        float a0 = 0.f, a1 = 0.f, a2 = 0.f, a3 = 0.f, cb = 0.f;
        const float* wro = wf + o * 256;     // left half cols 0..127 (L2-hot)
        int i0 = half * 4;
        for (int c = 0; c < 128; c++) {
            float f = wro[c];
            const float* wr = w1s + c * 8 + i0;
            a0 += f * wr[0]; a1 += f * wr[1]; a2 += f * wr[2]; a3 += f * wr[3];
            if (half) cb += f * c1s[c];
        }
        w1fS[o][i0] = a0; w1fS[o][i0 + 1] = a1; w1fS[o][i0 + 2] = a2; w1fS[o][i0 + 3] = a3;
        if (half) cbS[o] = cb;
    }
    __syncthreads();

    if (t < 128) {
        int o = t;
        float s3 = g3[o] * rsqrtf(v3[o] + EPSV);
        float be3 = b3[o] - m3[o] * s3;
        float csum = 0.f;
        #pragma unroll
        for (int i = 0; i < 8; i++) {
            float wv = wA[o * 8 + i];
            A3L[o * 32 + i] = f2bf(s3 * wv * s2[i] * s1[i]);
            csum += wv * be2[i];
        }
        A3L[o * 32 + 8] = f2bf(s3 * csum + be3);   // c3 folded as ones-channel
        for (int k = 9; k < 32; k++) A3L[o * 32 + k] = 0;

        float bs = bfv[o] + cbS[o];
        #pragma unroll
        for (int i = 0; i < 8; i++) {
            float w1f = w1fS[o][i];
            bs += w1f * be1[i];
            Wc[o * 160 + 128 + i] = f2bf(w1f * s1[i]);
        }
        Wc[o * 160 + 136] = f2bf(bs);
        for (int k = 137; k < 160; k++) Wc[o * 160 + k] = 0;
    }
}

// ---------------- heavy v11: v10 + T5 setprio on MFMA clusters + max3 trees ----
// R9 analysis: no saturated resource (per-SIMD MFMA 9%, VALU 12%, LDS ~27%+pump;
// "conflicts" counter = phantom b128 pumping — bank-audit shows all ops at the
// data floor). S2 is at both the MFMA-count floor and the LDS-read floor for
// this decomposition. Remaining regime: dependency chains + barrier lockstep
// with 6 independent blocks/CU at different phases -> T5 s_setprio(1) around
// the MFMA clusters lets the CU scheduler prefer MFMA-entering waves (+4-7% in
// the structurally analogous attn case, m191/m218b). fmax trees in max3-triple
// form (clang fuses to v_max3_f32). Everything else identical to R9.
#define S1(P, BUF)                                                            \
    {                                                                         \
        U4 bfr;                                                               \
        if (hi == 0) bfr.q = DXs[((P) << 5) + l31];                           \
        else         bfr.q = make_uint4(0x00003F80u, 0u, 0u, 0u);             \
        f32x16 z = {};                                                        \
        __builtin_amdgcn_s_setprio(1);                                        \
        z = __builtin_amdgcn_mfma_f32_32x32x16_bf16(a3f, bfr.v, z, 0, 0, 0);  \
        __builtin_amdgcn_s_setprio(0);                                        \
        u32* ab = (u32*)Abuf + (BUF) * 2048 + (l31 << 6) + (hi << 1);         \
        _Pragma("unroll")                                                     \
        for (int gi = 0; gi < 4; gi++) {                                      \
            u32 plo, phi;                                                     \
            asm("v_cvt_pk_bf16_f32 %0, %1, %2" : "=v"(plo)                    \
                : "v"(fmaxf(z[4 * gi + 0], 0.f)), "v"(fmaxf(z[4 * gi + 1], 0.f))); \
            asm("v_cvt_pk_bf16_f32 %0, %1, %2" : "=v"(phi)                    \
                : "v"(fmaxf(z[4 * gi + 2], 0.f)), "v"(fmaxf(z[4 * gi + 3], 0.f))); \
            int gsw = (((w << 2) + gi) ^ (l31 & 7)) << 2;                     \
            *(uint2*)(ab + gsw) = make_uint2(plo, phi);                       \
        }                                                                     \
    }

#define S2(P, BUF)                                                            \
    {                                                                         \
        f32x16 acc = {};                                                      \
        __builtin_amdgcn_s_setprio(1);                                        \
        _Pragma("unroll")                                                     \
        for (int kt = 0; kt < 8; ++kt) {                                      \
            U4 a; a.q = Abuf[BUF][l31][((kt << 1) + hi) ^ (l31 & 7)];         \
            acc = __builtin_amdgcn_mfma_f32_32x32x16_bf16(a.v, wBf[kt], acc, 0, 0, 0); \
        }                                                                     \
        __builtin_amdgcn_s_setprio(0);                                        \
        float me = max3f(acc[0], acc[1], acc[2]);                             \
        me = max3f(me, acc[3], acc[4]);                                       \
        me = max3f(me, acc[5], acc[6]);                                       \
        me = fmaxf(me, acc[7]);                                               \
        float mo = max3f(acc[8], acc[9], acc[10]);                            \
        mo = max3f(mo, acc[11], acc[12]);                                     \
        mo = max3f(mo, acc[13], acc[14]);                                     \
        mo = fmaxf(mo, acc[15]);                                              \
        me = fmaxf(me, __shfl_xor(me, 32, 64));                               \
        mo = fmaxf(mo, __shfl_xor(mo, 32, 64));                               \
        float mv = hi ? mo : me;                                              \
        NEu16[(((P) << 1) + hi) * 168 + (w << 5) + l31] =                     \
            (u16)((__float_as_uint(mv) + 0x8000u) >> 16);                     \
    }

__global__ __launch_bounds__(256, 6) void heavy_kernel(
    const float* __restrict__ xh, const int* __restrict__ nbr,
    const u16* __restrict__ A3Lg, const u16* __restrict__ wBh,
    const u16* __restrict__ Wcat, float* __restrict__ out)
{
    __shared__ uint4 DXs[256];             // [row] dx bf16x8, 4KB
    __shared__ uint4 Abuf[2][32][16];      // z dbuf [buf][slot32][granule^swz], 16KB
    __shared__ uint4 NExq[16 * 21];        // [pt][NE(128)|x(8)|1|0...], 5.25KB
    u16* NEu16 = (u16*)NExq;
    int t = threadIdx.x;
    int w = t >> 6, l = t & 63;
    int l31 = l & 31, hi = l >> 5;
    int quad = l >> 4, l15 = l & 15;       // epilogue (16x16 path)

    // persistent wB^T B-frags (32x32x16): B[col=32w+l31][k=kt*16+hi*8+j], 32 regs
    bf16x8 wBf[8];
    #pragma unroll
    for (int kt = 0; kt < 8; kt++) {
        U4 u; u.q = *(const uint4*)(wBh + (w * 32 + l31) * 128 + kt * 16 + hi * 8);
        wBf[kt] = u.v;
    }
    // persistent S1 A-frag: A3L[row=32w+l31][k=hi*8+j], 4 regs
    bf16x8 a3f;
    {
        U4 u; u.q = *(const uint4*)(A3Lg + ((w * 32 + l31) << 5) + hi * 8);
        a3f = u.v;
    }

    int pbase = blockIdx.x << 4;           // 16 points per block, batch-aligned
    int b = pbase >> 16;
    int n0 = pbase & 65535;
    const float4* xq = (const float4*)xh + ((size_t)b << 17);

    // zero NExq pad region (Wcat cols 137..159 are zero, but 0 x NaN = NaN)
    for (int j = t; j < 336; j += 256) NExq[j] = make_uint4(0u, 0u, 0u, 0u);

    // ---- phase A: gather all 256 Delta-rows (32B f32 each; 4MB/batch working
    // set -> L2-resident, proven R6: FETCH 254->40MB) ----
    {
        int pt = t >> 4, slot = t & 15;
        int srow = (slot < 15) ? slot + 1 : 1;     // slot 15 dups neighbor row 1
        int idx = nbr[(b << 20) | (srow << 16) | (n0 + pt)];
        float4 ga = xq[(u32)(idx << 1)], gb = xq[(u32)((idx << 1) + 1)];
        float4 ca = xq[(u32)((n0 + pt) << 1)], cb = xq[(u32)(((n0 + pt) << 1) + 1)];
        uint4 d;
        d.x = pack_rne(ga.x - ca.x, ga.y - ca.y);
        d.y = pack_rne(ga.z - ca.z, ga.w - ca.w);
        d.z = pack_rne(gb.x - cb.x, gb.y - cb.y);
        d.w = pack_rne(gb.z - cb.z, gb.w - cb.w);
        DXs[t] = d;
    }
    __syncthreads();

    // 8 point-pairs, double-buffered: S1(next pair) || S2(current pair)
    S1(0, 0)
    __syncthreads();
    for (int p = 0; p < 8; ++p) {
        if (p < 7) S1(p + 1, (p + 1) & 1)
        S2(p, p & 1)
        __syncthreads();
    }

    // ---- fused combine epilogue: out = Wcat @ [NE; x_bf16; 1; 0] ----
    if (t < 16) {
        const float4* xr = xq + ((u32)(n0 + t) << 1);
        float4 xa = xr[0], xb = xr[1];
        u32* dst = (u32*)NExq + t * 84 + 64;
        dst[0] = pack_rne(xa.x, xa.y);
        dst[1] = pack_rne(xa.z, xa.w);
        dst[2] = pack_rne(xb.x, xb.y);
        dst[3] = pack_rne(xb.z, xb.w);
        dst[4] = 0x3F80u;                  // the "1.0" slot (ch136)
    }
    __syncthreads();

    bf16x8 Wcf[2][5];
    #pragma unroll
    for (int mt = 0; mt < 2; mt++)
        #pragma unroll
        for (int kt = 0; kt < 5; kt++) {
            U4 u; u.q = *(const uint4*)(Wcat + (w * 32 + mt * 16 + l15) * 160 + kt * 32 + quad * 8);
            Wcf[mt][kt] = u.v;
        }
    f32x4 oa[2];
    oa[0] = (f32x4){0.f, 0.f, 0.f, 0.f};
    oa[1] = (f32x4){0.f, 0.f, 0.f, 0.f};
    __builtin_amdgcn_s_setprio(1);
    #pragma unroll
    for (int kt = 0; kt < 5; ++kt) {
        U4 u; u.q = NExq[l15 * 21 + kt * 4 + quad];
        oa[0] = __builtin_amdgcn_mfma_f32_16x16x32_bf16(Wcf[0][kt], u.v, oa[0], 0, 0, 0);
        oa[1] = __builtin_amdgcn_mfma_f32_16x16x32_bf16(Wcf[1][kt], u.v, oa[1], 0, 0, 0);
    }
    __builtin_amdgcn_s_setprio(0);
    #pragma unroll
    for (int mt = 0; mt < 2; ++mt) {
        int ob = w * 32 + mt * 16 + quad * 4;
        #pragma unroll
        for (int r = 0; r < 4; ++r)
            out[(((b << 7) + ob + r) << 16) + n0 + l15] = oa[mt][r];
    }
}

extern "C" void kernel_launch(void* const* d_in, const int* in_sizes, int n_in,
                              void* d_out, int out_size, void* d_ws, size_t ws_size,
                              hipStream_t stream) {
    const float* x   = (const float*)d_in[0];
    const int*   nbr = (const int*)d_in[1];
    const float* g1  = (const float*)d_in[2];
    const float* b1  = (const float*)d_in[3];
    const float* m1  = (const float*)d_in[4];
    const float* v1  = (const float*)d_in[5];
    const float* w1  = (const float*)d_in[6];
    const float* c1b = (const float*)d_in[7];
    const float* g2  = (const float*)d_in[8];
    const float* b2  = (const float*)d_in[9];
    const float* m2  = (const float*)d_in[10];
    const float* v2  = (const float*)d_in[11];
    const float* wA  = (const float*)d_in[12];
    const float* g3  = (const float*)d_in[13];
    const float* b3  = (const float*)d_in[14];
    const float* m3  = (const float*)d_in[15];
    const float* v3  = (const float*)d_in[16];
    const float* wB  = (const float*)d_in[17];
    const float* wf  = (const float*)d_in[18];
    const float* bfv = (const float*)d_in[19];

    u16*   A3L  = (u16*)((char*)d_ws + WS_A3L);
    u16*   wBh  = (u16*)((char*)d_ws + WS_WB);
    u16*   Wcat = (u16*)((char*)d_ws + WS_WCAT);
    float* xh   = (float*)((char*)d_ws + WS_XH);
    float* out  = (float*)d_out;

    setup_kernel<<<544, 256, 0, stream>>>(x, g1, b1, m1, v1, w1, c1b,
                                          g2, b2, m2, v2, wA, g3, b3, m3, v3,
                                          wB, wf, bfv, xh, A3L, wBh, Wcat);
    heavy_kernel<<<8192, 256, 0, stream>>>(xh, nbr, A3L, wBh, Wcat, out);
}

// Round 11
// 223.465 us; speedup vs baseline: 1.0149x; 1.0149x over previous
//
#include <hip/hip_runtime.h>
#include <hip/hip_bf16.h>

typedef unsigned short u16;
typedef unsigned int u32;
typedef short bf16x8 __attribute__((ext_vector_type(8)));
typedef float f32x4 __attribute__((ext_vector_type(4)));
typedef float f32x16 __attribute__((ext_vector_type(16)));

#define EPSV 1e-5f
// ws byte layout
#define WS_A3L   0                       // 128*32 bf16 [A3 | c3 | 0...] = 8 KB
#define WS_WB    8192                    // 128*128 bf16 = 32 KB
#define WS_WCAT  40960                   // 128*160 bf16 [wf2 | A1 | bias | 0] = 40 KB
#define WS_XH    81920                   // 2*65536*8 f32 x-transpose = 4 MB

union U4 { uint4 q; bf16x8 v; };

__device__ __forceinline__ u16 f2bf(float f) {
    union { __hip_bfloat16 h; u16 u; } cv;
    cv.h = __float2bfloat16(f);
    return cv.u;
}
// RNE pack of two f32 into packed bf16 pair (lo = a, hi = b) — pure integer ops
__device__ __forceinline__ u32 pack_rne(float a, float b) {
    u32 ua = __float_as_uint(a), ub = __float_as_uint(b);
    ua = ua + 0x7FFFu + ((ua >> 16) & 1u);
    ub = ub + 0x7FFFu + ((ub >> 16) & 1u);
    return (ua >> 16) | (ub & 0xFFFF0000u);
}

// ---------------- setup: xhat (blocks 0..511) + prep (blocks 512..543) ----------
__global__ __launch_bounds__(256) void setup_kernel(
    const float* __restrict__ x,
    const float* g1, const float* b1, const float* m1, const float* v1,
    const float* w1, const float* c1b,
    const float* g2, const float* b2, const float* m2, const float* v2,
    const float* wA,
    const float* g3, const float* b3, const float* m3, const float* v3,
    const float* wB, const float* wf, const float* bfv,
    float* __restrict__ xh, u16* A3L, u16* wBh, u16* Wc)
{
    __shared__ float w1s[1024];
    __shared__ float c1s[128];
    __shared__ float s1[8], be1[8], s2[8], be2[8];
    __shared__ float w1fS[128][8];
    __shared__ float cbS[128];
    int bid = blockIdx.x, t = threadIdx.x;

    if (bid < 512) {
        // xhat: x transpose to [b][n][8ch] f32 rows (32B)
        int tg = (bid << 8) + t;
        int b = tg >> 16, n = tg & 65535;
        float4 a, c;
        a.x = x[(((b << 3) + 0) << 16) | n];
        a.y = x[(((b << 3) + 1) << 16) | n];
        a.z = x[(((b << 3) + 2) << 16) | n];
        a.w = x[(((b << 3) + 3) << 16) | n];
        c.x = x[(((b << 3) + 4) << 16) | n];
        c.y = x[(((b << 3) + 5) << 16) | n];
        c.z = x[(((b << 3) + 6) << 16) | n];
        c.w = x[(((b << 3) + 7) << 16) | n];
        float4* o = (float4*)xh + ((size_t)tg << 1);
        o[0] = a; o[1] = c;
        return;
    }
    int rb = bid - 512;                 // 0..31
    // distributed big copies (32 blocks)
    for (int j = (rb << 8) + t; j < 16384; j += 8192) {
        int o = j >> 7, c = j & 127;
        Wc[o * 160 + c] = f2bf(wf[o * 256 + 128 + c]);
    }
    {
        int j = (rb << 8) + t;          // 8192 packed u32 over 8192 threads
        ((u32*)wBh)[j] = pack_rne(wB[2 * j], wB[2 * j + 1]);
    }
    if (rb) return;

    // ---- fold (single block) ----
    for (int i = t; i < 1024; i += 256) w1s[i] = w1[i];
    if (t < 128) c1s[t] = c1b[t];
    if (t < 8) {
        float s = g1[t] * rsqrtf(v1[t] + EPSV); s1[t] = s; be1[t] = b1[t] - m1[t] * s;
        float u = g2[t] * rsqrtf(v2[t] + EPSV); s2[t] = u; be2[t] = b2[t] - m2[t] * u;
    }
    __syncthreads();

    // fold wf_left @ [w1 | c1b]: thread (o, half) does 4 i's (+ cb on half 1)
    {
        int o = t >> 1, half = t & 1;
        float a0 = 0.f, a1 = 0.f, a2 = 0.f, a3 = 0.f, cb = 0.f;
        const float* wro = wf + o * 256;     // left half cols 0..127 (L2-hot)
        int i0 = half * 4;
        for (int c = 0; c < 128; c++) {
            float f = wro[c];
            const float* wr = w1s + c * 8 + i0;
            a0 += f * wr[0]; a1 += f * wr[1]; a2 += f * wr[2]; a3 += f * wr[3];
            if (half) cb += f * c1s[c];
        }
        w1fS[o][i0] = a0; w1fS[o][i0 + 1] = a1; w1fS[o][i0 + 2] = a2; w1fS[o][i0 + 3] = a3;
        if (half) cbS[o] = cb;
    }
    __syncthreads();

    if (t < 128) {
        int o = t;
        float s3 = g3[o] * rsqrtf(v3[o] + EPSV);
        float be3 = b3[o] - m3[o] * s3;
        float csum = 0.f;
        #pragma unroll
        for (int i = 0; i < 8; i++) {
            float wv = wA[o * 8 + i];
            A3L[o * 32 + i] = f2bf(s3 * wv * s2[i] * s1[i]);
            csum += wv * be2[i];
        }
        A3L[o * 32 + 8] = f2bf(s3 * csum + be3);   // c3 folded as ones-channel
        for (int k = 9; k < 32; k++) A3L[o * 32 + k] = 0;

        float bs = bfv[o] + cbS[o];
        #pragma unroll
        for (int i = 0; i < 8; i++) {
            float w1f = w1fS[o][i];
            bs += w1f * be1[i];
            Wc[o * 160 + 128 + i] = f2bf(w1f * s1[i]);
        }
        Wc[o * 160 + 136] = f2bf(bs);
        for (int k = 137; k < 160; k++) Wc[o * 160 + k] = 0;
    }
}

// ---------------- heavy v12: R9 core (setprio REVERTED) + 32 points/block -------
// R10 lesson: setprio skewed cross-block timing -> L2 merge window broke (WRITE
// 65->98MB, FETCH 34->53MB, +13.8us). Reverted. This round amortizes per-block
// fixed costs (77KB weight loads: wBf 32KB + Wcat 40KB + A3L; prologue/epilogue
// drains) over 2x points: grid 8192->4096, 32 pts/block, 16 pairs, DXs 512 rows
// (2 gathers/thread), NExq 32x21, epilogue = two 16-pt passes under ONE Wcat
// load. LDS 35.3KB -> 4 blocks/CU (occupancy trade this round tests).
// S1/S2 fragment maps unchanged from R9 (verified: absmax 0.0039).
#define S1(P, BUF)                                                            \
    {                                                                         \
        U4 bfr;                                                               \
        if (hi == 0) bfr.q = DXs[((P) << 5) + l31];                           \
        else         bfr.q = make_uint4(0x00003F80u, 0u, 0u, 0u);             \
        f32x16 z = {};                                                        \
        z = __builtin_amdgcn_mfma_f32_32x32x16_bf16(a3f, bfr.v, z, 0, 0, 0);  \
        u32* ab = (u32*)Abuf + (BUF) * 2048 + (l31 << 6) + (hi << 1);         \
        _Pragma("unroll")                                                     \
        for (int gi = 0; gi < 4; gi++) {                                      \
            u32 plo, phi;                                                     \
            asm("v_cvt_pk_bf16_f32 %0, %1, %2" : "=v"(plo)                    \
                : "v"(fmaxf(z[4 * gi + 0], 0.f)), "v"(fmaxf(z[4 * gi + 1], 0.f))); \
            asm("v_cvt_pk_bf16_f32 %0, %1, %2" : "=v"(phi)                    \
                : "v"(fmaxf(z[4 * gi + 2], 0.f)), "v"(fmaxf(z[4 * gi + 3], 0.f))); \
            int gsw = (((w << 2) + gi) ^ (l31 & 7)) << 2;                     \
            *(uint2*)(ab + gsw) = make_uint2(plo, phi);                       \
        }                                                                     \
    }

#define S2(P, BUF)                                                            \
    {                                                                         \
        f32x16 acc = {};                                                      \
        _Pragma("unroll")                                                     \
        for (int kt = 0; kt < 8; ++kt) {                                      \
            U4 a; a.q = Abuf[BUF][l31][((kt << 1) + hi) ^ (l31 & 7)];         \
            acc = __builtin_amdgcn_mfma_f32_32x32x16_bf16(a.v, wBf[kt], acc, 0, 0, 0); \
        }                                                                     \
        float me = fmaxf(fmaxf(fmaxf(acc[0], acc[1]), fmaxf(acc[2], acc[3])), \
                         fmaxf(fmaxf(acc[4], acc[5]), fmaxf(acc[6], acc[7]))); \
        float mo = fmaxf(fmaxf(fmaxf(acc[8], acc[9]), fmaxf(acc[10], acc[11])), \
                         fmaxf(fmaxf(acc[12], acc[13]), fmaxf(acc[14], acc[15]))); \
        me = fmaxf(me, __shfl_xor(me, 32, 64));                               \
        mo = fmaxf(mo, __shfl_xor(mo, 32, 64));                               \
        float mv = hi ? mo : me;                                              \
        NEu16[(((P) << 1) + hi) * 168 + (w << 5) + l31] =                     \
            (u16)((__float_as_uint(mv) + 0x8000u) >> 16);                     \
    }

__global__ __launch_bounds__(256, 4) void heavy_kernel(
    const float* __restrict__ xh, const int* __restrict__ nbr,
    const u16* __restrict__ A3Lg, const u16* __restrict__ wBh,
    const u16* __restrict__ Wcat, float* __restrict__ out)
{
    __shared__ uint4 DXs[512];             // [row] dx bf16x8, 8KB (32 pts x 16 slots)
    __shared__ uint4 Abuf[2][32][16];      // z dbuf [buf][slot32][granule^swz], 16KB
    __shared__ uint4 NExq[32 * 21];        // [pt][NE(128)|x(8)|1|0...], 10.5KB
    u16* NEu16 = (u16*)NExq;
    int t = threadIdx.x;
    int w = t >> 6, l = t & 63;
    int l31 = l & 31, hi = l >> 5;
    int quad = l >> 4, l15 = l & 15;       // epilogue (16x16 path)

    // persistent wB^T B-frags (32x32x16): B[col=32w+l31][k=kt*16+hi*8+j], 32 regs
    bf16x8 wBf[8];
    #pragma unroll
    for (int kt = 0; kt < 8; kt++) {
        U4 u; u.q = *(const uint4*)(wBh + (w * 32 + l31) * 128 + kt * 16 + hi * 8);
        wBf[kt] = u.v;
    }
    // persistent S1 A-frag: A3L[row=32w+l31][k=hi*8+j], 4 regs
    bf16x8 a3f;
    {
        U4 u; u.q = *(const uint4*)(A3Lg + ((w * 32 + l31) << 5) + hi * 8);
        a3f = u.v;
    }

    int pbase = blockIdx.x << 5;           // 32 points per block, batch-aligned
    int b = pbase >> 16;
    int n0 = pbase & 65535;
    const float4* xq = (const float4*)xh + ((size_t)b << 17);

    // zero NExq (incl. pad cols 137..159: Wcat cols are zero, but 0 x NaN = NaN)
    for (int j = t; j < 672; j += 256) NExq[j] = make_uint4(0u, 0u, 0u, 0u);

    // ---- phase A: gather all 512 Delta-rows (32B f32 each; 4MB/batch working
    // set -> L2-resident, proven R6: FETCH 254->40MB). 2 rows/thread. ----
    for (int r = t; r < 512; r += 256) {
        int pt = r >> 4, slot = r & 15;
        int srow = (slot < 15) ? slot + 1 : 1;     // slot 15 dups neighbor row 1
        int idx = nbr[(b << 20) | (srow << 16) | (n0 + pt)];
        float4 ga = xq[(u32)(idx << 1)], gb = xq[(u32)((idx << 1) + 1)];
        float4 ca = xq[(u32)((n0 + pt) << 1)], cb = xq[(u32)(((n0 + pt) << 1) + 1)];
        uint4 d;
        d.x = pack_rne(ga.x - ca.x, ga.y - ca.y);
        d.y = pack_rne(ga.z - ca.z, ga.w - ca.w);
        d.z = pack_rne(gb.x - cb.x, gb.y - cb.y);
        d.w = pack_rne(gb.z - cb.z, gb.w - cb.w);
        DXs[r] = d;
    }
    __syncthreads();

    // 16 point-pairs, double-buffered: S1(next pair) || S2(current pair)
    S1(0, 0)
    __syncthreads();
    for (int p = 0; p < 16; ++p) {
        if (p < 15) S1(p + 1, (p + 1) & 1)
        S2(p, p & 1)
        __syncthreads();
    }

    // ---- fused combine epilogue: out = Wcat @ [NE; x_bf16; 1; 0], 2 passes ----
    if (t < 32) {
        const float4* xr = xq + ((u32)(n0 + t) << 1);
        float4 xa = xr[0], xb = xr[1];
        u32* dst = (u32*)NExq + t * 84 + 64;
        dst[0] = pack_rne(xa.x, xa.y);
        dst[1] = pack_rne(xa.z, xa.w);
        dst[2] = pack_rne(xb.x, xb.y);
        dst[3] = pack_rne(xb.z, xb.w);
        dst[4] = 0x3F80u;                  // the "1.0" slot (ch136)
    }
    __syncthreads();

    bf16x8 Wcf[2][5];
    #pragma unroll
    for (int mt = 0; mt < 2; mt++)
        #pragma unroll
        for (int kt = 0; kt < 5; kt++) {
            U4 u; u.q = *(const uint4*)(Wcat + (w * 32 + mt * 16 + l15) * 160 + kt * 32 + quad * 8);
            Wcf[mt][kt] = u.v;
        }
    #pragma unroll
    for (int g = 0; g < 2; ++g) {
        f32x4 oa[2];
        oa[0] = (f32x4){0.f, 0.f, 0.f, 0.f};
        oa[1] = (f32x4){0.f, 0.f, 0.f, 0.f};
        #pragma unroll
        for (int kt = 0; kt < 5; ++kt) {
            U4 u; u.q = NExq[((g << 4) + l15) * 21 + kt * 4 + quad];
            oa[0] = __builtin_amdgcn_mfma_f32_16x16x32_bf16(Wcf[0][kt], u.v, oa[0], 0, 0, 0);
            oa[1] = __builtin_amdgcn_mfma_f32_16x16x32_bf16(Wcf[1][kt], u.v, oa[1], 0, 0, 0);
        }
        #pragma unroll
        for (int mt = 0; mt < 2; ++mt) {
            int ob = w * 32 + mt * 16 + quad * 4;
            #pragma unroll
            for (int r = 0; r < 4; ++r)
                out[(((b << 7) + ob + r) << 16) + n0 + (g << 4) + l15] = oa[mt][r];
        }
    }
}

extern "C" void kernel_launch(void* const* d_in, const int* in_sizes, int n_in,
                              void* d_out, int out_size, void* d_ws, size_t ws_size,
                              hipStream_t stream) {
    const float* x   = (const float*)d_in[0];
    const int*   nbr = (const int*)d_in[1];
    const float* g1  = (const float*)d_in[2];
    const float* b1  = (const float*)d_in[3];
    const float* m1  = (const float*)d_in[4];
    const float* v1  = (const float*)d_in[5];
    const float* w1  = (const float*)d_in[6];
    const float* c1b = (const float*)d_in[7];
    const float* g2  = (const float*)d_in[8];
    const float* b2  = (const float*)d_in[9];
    const float* m2  = (const float*)d_in[10];
    const float* v2  = (const float*)d_in[11];
    const float* wA  = (const float*)d_in[12];
    const float* g3  = (const float*)d_in[13];
    const float* b3  = (const float*)d_in[14];
    const float* m3  = (const float*)d_in[15];
    const float* v3  = (const float*)d_in[16];
    const float* wB  = (const float*)d_in[17];
    const float* wf  = (const float*)d_in[18];
    const float* bfv = (const float*)d_in[19];

    u16*   A3L  = (u16*)((char*)d_ws + WS_A3L);
    u16*   wBh  = (u16*)((char*)d_ws + WS_WB);
    u16*   Wcat = (u16*)((char*)d_ws + WS_WCAT);
    float* xh   = (float*)((char*)d_ws + WS_XH);
    float* out  = (float*)d_out;

    setup_kernel<<<544, 256, 0, stream>>>(x, g1, b1, m1, v1, w1, c1b,
                                          g2, b2, m2, v2, wA, g3, b3, m3, v3,
                                          wB, wf, bfv, xh, A3L, wBh, Wcat);
    heavy_kernel<<<4096, 256, 0, stream>>>(xh, nbr, A3L, wBh, Wcat, out);
}